// Round 1
// 540.348 us; speedup vs baseline: 1.0004x; 1.0004x over previous
//
#include <hip/hip_runtime.h>

#define NN 50000
#define NE 800000
#define C 128

typedef __attribute__((ext_vector_type(8))) short short8_t;
typedef __attribute__((ext_vector_type(4))) float f32x4;
typedef __attribute__((ext_vector_type(2))) _Float16 half2_t;
typedef __attribute__((ext_vector_type(8))) _Float16 half8_t;

__device__ __forceinline__ unsigned short f2h_u(float f) {
    _Float16 h = (_Float16)f;
    union { _Float16 h; unsigned short u; } v; v.h = h; return v.u;
}

__device__ __forceinline__ float fdot2(half2_t a, half2_t b, float c) {
#if __has_builtin(__builtin_amdgcn_fdot2)
    return __builtin_amdgcn_fdot2(a, b, c, false);
#else
    return c + (float)a.x * (float)b.x + (float)a.y * (float)b.y;
#endif
}

// ---------------- CSR build ----------------
__global__ void count_deg(const int* __restrict__ row, int* __restrict__ deg) {
    int e = blockIdx.x * blockDim.x + threadIdx.x;
    if (e < NE) atomicAdd(&deg[row[e]], 1);
}

#define SCAN_NB ((NN + 1023) / 1024)

__global__ void deg_block_sums(const int* __restrict__ deg, int* __restrict__ bsum) {
    __shared__ int sred[256];
    int t = threadIdx.x;
    int base = blockIdx.x * 1024 + t * 4;
    int s = 0;
    if (base + 3 < NN) {
        int4 v = *(const int4*)(deg + base);
        s = v.x + v.y + v.z + v.w;
    } else {
        for (int i = 0; i < 4; ++i) if (base + i < NN) s += deg[base + i];
    }
    sred[t] = s; __syncthreads();
    for (int off = 128; off > 0; off >>= 1) {
        if (t < off) sred[t] += sred[t + off];
        __syncthreads();
    }
    if (t == 0) bsum[blockIdx.x] = sred[0];
}

__global__ void scan_bsums(int* __restrict__ bsum) {   // 1 block x 64
    int t = threadIdx.x;
    int v = (t < SCAN_NB) ? bsum[t] : 0;
#pragma unroll
    for (int off = 1; off < 64; off <<= 1) {
        int u = __shfl_up(v, off, 64);
        if (t >= off) v += u;
    }
    int ex = __shfl_up(v, 1, 64);
    if (t == 0) ex = 0;
    if (t < SCAN_NB) bsum[t] = ex;
}

__global__ void scan_within(const int* __restrict__ deg, const int* __restrict__ bsum,
                            int* __restrict__ offsets, int* __restrict__ cursor) {
    __shared__ int sdat[256];
    int t = threadIdx.x;
    int base = blockIdx.x * 1024 + t * 4;
    int d[4] = {0, 0, 0, 0};
    if (base + 3 < NN) {
        int4 v = *(const int4*)(deg + base);
        d[0] = v.x; d[1] = v.y; d[2] = v.z; d[3] = v.w;
    } else {
        for (int i = 0; i < 4; ++i) if (base + i < NN) d[i] = deg[base + i];
    }
    sdat[t] = d[0] + d[1] + d[2] + d[3];
    __syncthreads();
    for (int off = 1; off < 256; off <<= 1) {
        int v = sdat[t];
        int add = (t >= off) ? sdat[t - off] : 0;
        __syncthreads();
        sdat[t] = v + add;
        __syncthreads();
    }
    int run = bsum[blockIdx.x] + ((t == 0) ? 0 : sdat[t - 1]);
    for (int i = 0; i < 4; ++i) {
        int idx = base + i;
        if (idx < NN) { offsets[idx] = run; cursor[idx] = run; run += d[i]; }
    }
    if (blockIdx.x == 0 && t == 0) offsets[NN] = NE;
}

__global__ void bucket_edges(const int* __restrict__ row, const int* __restrict__ col,
                             int* __restrict__ cursor, int* __restrict__ colv) {
    int e = blockIdx.x * blockDim.x + threadIdx.x;
    if (e < NE) {
        int r = row[e];
        int p = atomicAdd(&cursor[r], 1);
        colv[p] = col[e];
    }
}

// ---------------- cast x -> fp16 AND per-node stats (packed float2) ----------------
__global__ void cast_stats(const float* __restrict__ x, unsigned short* __restrict__ xh,
                           float2* __restrict__ st1) {
    int node = blockIdx.x * 4 + (threadIdx.x >> 6);
    int lane = threadIdx.x & 63;
    float2 v = *(const float2*)(x + (size_t)node * C + lane * 2);
    half2_t h; h.x = (_Float16)v.x; h.y = (_Float16)v.y;
    *(half2_t*)(xh + (size_t)node * C + lane * 2) = h;
    float sq = v.x * v.x + v.y * v.y;
    float sm = v.x + v.y;
#pragma unroll
    for (int off = 32; off > 0; off >>= 1) {
        sq += __shfl_xor(sq, off, 64);
        sm += __shfl_xor(sm, off, 64);
    }
    if (lane == 0) st1[node] = make_float2(sq, sm);
}

// ---------------- layer-2 stats (packed float4: n2_3, n2_4, s1_4) ----------------
__global__ void stats2(const float* __restrict__ x3, const float* __restrict__ x4,
                       float4* __restrict__ st2) {
    int node = blockIdx.x * 4 + (threadIdx.x >> 6);
    int lane = threadIdx.x & 63;
    float2 a = *(const float2*)(x3 + (size_t)node * C + lane * 2);
    float2 b = *(const float2*)(x4 + (size_t)node * C + lane * 2);
    float q3 = a.x * a.x + a.y * a.y;
    float q4 = b.x * b.x + b.y * b.y;
    float m4 = b.x + b.y;
#pragma unroll
    for (int off = 32; off > 0; off >>= 1) {
        q3 += __shfl_xor(q3, off, 64);
        q4 += __shfl_xor(q4, off, 64);
        m4 += __shfl_xor(m4, off, 64);
    }
    if (lane == 0) st2[node] = make_float4(q3, q4, m4, 0.f);
}

// ---------------- weight prep (GEMM weights + attention W1), fused ----------------
__global__ void prep_weights(const float* __restrict__ Wl0, const float* __restrict__ Wr0,
                             const float* __restrict__ Wl1, const float* __restrict__ Wr1,
                             const float* __restrict__ aW1,
                             unsigned short* __restrict__ Bt, unsigned short* __restrict__ BtA) {
    int id = blockIdx.x * 256 + threadIdx.x;   // [0, 65536+8192)
    if (id < 65536) {
        int layer = id >> 15;
        int c = (id >> 14) & 1;
        int n = (id >> 7) & 127;
        int kk = id & 127;
        const float* W = layer == 0 ? (c == 0 ? Wl0 : Wr0) : (c == 0 ? Wl1 : Wr1);
        Bt[id] = f2h_u(W[kk * 128 + n]);
    } else {
        int a = id - 65536;                    // [0, 8192)
        int col = a >> 7, k = a & 127;
        BtA[a] = f2h_u(aW1[k * 64 + col]);
    }
}

// ---------------- FUSED layer 1: edge sim + weighted aggregate in one gather pass ----
// One wave per node. Lane owns 2 channels. Per edge: gather x[c] once, wave-reduce
// the dot, compute both cos & eud weights, accumulate both weighted sums.
__global__ __launch_bounds__(256) void fused_l1(
    const unsigned short* __restrict__ xh, const int* __restrict__ colv,
    const int* __restrict__ offsets, const float2* __restrict__ st1,
    unsigned short* __restrict__ aggc, unsigned short* __restrict__ agge) {
    int node = blockIdx.x * 4 + (threadIdx.x >> 6);
    int lane = threadIdx.x & 63;
    int beg = offsets[node], end = offsets[node + 1];
    half2_t xr = *(const half2_t*)(xh + (size_t)node * C + lane * 2);
    float2 sr = st1[node];
    float n2r = sr.x, s1r = sr.y;
    float ac0 = 0.f, ac1 = 0.f, ae0 = 0.f, ae1 = 0.f;
    int p = beg;
    for (; p + 3 < end; p += 4) {
        int c0 = colv[p], c1 = colv[p + 1], c2 = colv[p + 2], c3 = colv[p + 3];
        half2_t u0 = *(const half2_t*)(xh + (size_t)c0 * C + lane * 2);
        half2_t u1 = *(const half2_t*)(xh + (size_t)c1 * C + lane * 2);
        half2_t u2 = *(const half2_t*)(xh + (size_t)c2 * C + lane * 2);
        half2_t u3 = *(const half2_t*)(xh + (size_t)c3 * C + lane * 2);
        float2 t0 = st1[c0], t1 = st1[c1], t2 = st1[c2], t3 = st1[c3];
        float d0 = fdot2(xr, u0, 0.f);
        float d1 = fdot2(xr, u1, 0.f);
        float d2 = fdot2(xr, u2, 0.f);
        float d3 = fdot2(xr, u3, 0.f);
#pragma unroll
        for (int off = 32; off > 0; off >>= 1) {
            d0 += __shfl_xor(d0, off, 64);
            d1 += __shfl_xor(d1, off, 64);
            d2 += __shfl_xor(d2, off, 64);
            d3 += __shfl_xor(d3, off, 64);
        }
        float wc0 = d0 / fmaxf(sqrtf(n2r * t0.x), 1e-8f);
        float wc1 = d1 / fmaxf(sqrtf(n2r * t1.x), 1e-8f);
        float wc2 = d2 / fmaxf(sqrtf(n2r * t2.x), 1e-8f);
        float wc3 = d3 / fmaxf(sqrtf(n2r * t3.x), 1e-8f);
        float q0 = n2r + t0.x - 2.f * d0 + 2e-6f * (s1r - t0.y) + 1.28e-10f;
        float q1 = n2r + t1.x - 2.f * d1 + 2e-6f * (s1r - t1.y) + 1.28e-10f;
        float q2 = n2r + t2.x - 2.f * d2 + 2e-6f * (s1r - t2.y) + 1.28e-10f;
        float q3 = n2r + t3.x - 2.f * d3 + 2e-6f * (s1r - t3.y) + 1.28e-10f;
        float we0 = sqrtf(fmaxf(q0, 0.f));
        float we1 = sqrtf(fmaxf(q1, 0.f));
        float we2 = sqrtf(fmaxf(q2, 0.f));
        float we3 = sqrtf(fmaxf(q3, 0.f));
        ac0 += wc0 * (float)u0.x + wc1 * (float)u1.x + wc2 * (float)u2.x + wc3 * (float)u3.x;
        ac1 += wc0 * (float)u0.y + wc1 * (float)u1.y + wc2 * (float)u2.y + wc3 * (float)u3.y;
        ae0 += we0 * (float)u0.x + we1 * (float)u1.x + we2 * (float)u2.x + we3 * (float)u3.x;
        ae1 += we0 * (float)u0.y + we1 * (float)u1.y + we2 * (float)u2.y + we3 * (float)u3.y;
    }
    for (; p < end; ++p) {
        int c0 = colv[p];
        half2_t u0 = *(const half2_t*)(xh + (size_t)c0 * C + lane * 2);
        float2 t0 = st1[c0];
        float d0 = fdot2(xr, u0, 0.f);
#pragma unroll
        for (int off = 32; off > 0; off >>= 1) d0 += __shfl_xor(d0, off, 64);
        float wc0 = d0 / fmaxf(sqrtf(n2r * t0.x), 1e-8f);
        float q0 = n2r + t0.x - 2.f * d0 + 2e-6f * (s1r - t0.y) + 1.28e-10f;
        float we0 = sqrtf(fmaxf(q0, 0.f));
        ac0 += wc0 * (float)u0.x; ac1 += wc0 * (float)u0.y;
        ae0 += we0 * (float)u0.x; ae1 += we0 * (float)u0.y;
    }
    float inv = 1.f / fmaxf((float)(end - beg), 1.f);
    ushort2 uc; uc.x = f2h_u(ac0 * inv); uc.y = f2h_u(ac1 * inv);
    ushort2 ue; ue.x = f2h_u(ae0 * inv); ue.y = f2h_u(ae1 * inv);
    *(ushort2*)(aggc + (size_t)node * C + lane * 2) = uc;
    *(ushort2*)(agge + (size_t)node * C + lane * 2) = ue;
}

// ---------------- FUSED layer 2: sim + aggregate, cos over x3 / eud over x4 ---------
__global__ __launch_bounds__(256) void fused_l2(
    const unsigned short* __restrict__ x3h, const unsigned short* __restrict__ x4h,
    const int* __restrict__ colv, const int* __restrict__ offsets,
    const float4* __restrict__ st2,
    unsigned short* __restrict__ agg1, unsigned short* __restrict__ agg2) {
    int node = blockIdx.x * 4 + (threadIdx.x >> 6);
    int lane = threadIdx.x & 63;
    int beg = offsets[node], end = offsets[node + 1];
    half2_t x3r = *(const half2_t*)(x3h + (size_t)node * C + lane * 2);
    half2_t x4r = *(const half2_t*)(x4h + (size_t)node * C + lane * 2);
    float4 sr = st2[node];   // (n2_3, n2_4, s1_4, -)
    float a10 = 0.f, a11 = 0.f, a20 = 0.f, a21 = 0.f;
    int p = beg;
    for (; p + 1 < end; p += 2) {
        int c0 = colv[p], c1 = colv[p + 1];
        half2_t u0 = *(const half2_t*)(x3h + (size_t)c0 * C + lane * 2);
        half2_t u1 = *(const half2_t*)(x3h + (size_t)c1 * C + lane * 2);
        half2_t v0 = *(const half2_t*)(x4h + (size_t)c0 * C + lane * 2);
        half2_t v1 = *(const half2_t*)(x4h + (size_t)c1 * C + lane * 2);
        float4 t0 = st2[c0], t1 = st2[c1];
        float d30 = fdot2(x3r, u0, 0.f);
        float d31 = fdot2(x3r, u1, 0.f);
        float d40 = fdot2(x4r, v0, 0.f);
        float d41 = fdot2(x4r, v1, 0.f);
#pragma unroll
        for (int off = 32; off > 0; off >>= 1) {
            d30 += __shfl_xor(d30, off, 64);
            d31 += __shfl_xor(d31, off, 64);
            d40 += __shfl_xor(d40, off, 64);
            d41 += __shfl_xor(d41, off, 64);
        }
        float wc0 = d30 / fmaxf(sqrtf(sr.x * t0.x), 1e-8f);
        float wc1 = d31 / fmaxf(sqrtf(sr.x * t1.x), 1e-8f);
        float q0 = sr.y + t0.y - 2.f * d40 + 2e-6f * (sr.z - t0.z) + 1.28e-10f;
        float q1 = sr.y + t1.y - 2.f * d41 + 2e-6f * (sr.z - t1.z) + 1.28e-10f;
        float we0 = sqrtf(fmaxf(q0, 0.f));
        float we1 = sqrtf(fmaxf(q1, 0.f));
        a10 += wc0 * (float)u0.x + wc1 * (float)u1.x;
        a11 += wc0 * (float)u0.y + wc1 * (float)u1.y;
        a20 += we0 * (float)v0.x + we1 * (float)v1.x;
        a21 += we0 * (float)v0.y + we1 * (float)v1.y;
    }
    if (p < end) {
        int c0 = colv[p];
        half2_t u0 = *(const half2_t*)(x3h + (size_t)c0 * C + lane * 2);
        half2_t v0 = *(const half2_t*)(x4h + (size_t)c0 * C + lane * 2);
        float4 t0 = st2[c0];
        float d30 = fdot2(x3r, u0, 0.f);
        float d40 = fdot2(x4r, v0, 0.f);
#pragma unroll
        for (int off = 32; off > 0; off >>= 1) {
            d30 += __shfl_xor(d30, off, 64);
            d40 += __shfl_xor(d40, off, 64);
        }
        float wc0 = d30 / fmaxf(sqrtf(sr.x * t0.x), 1e-8f);
        float q0 = sr.y + t0.y - 2.f * d40 + 2e-6f * (sr.z - t0.z) + 1.28e-10f;
        float we0 = sqrtf(fmaxf(q0, 0.f));
        a10 += wc0 * (float)u0.x; a11 += wc0 * (float)u0.y;
        a20 += we0 * (float)v0.x; a21 += we0 * (float)v0.y;
    }
    float inv = 1.f / fmaxf((float)(end - beg), 1.f);
    ushort2 u1o; u1o.x = f2h_u(a10 * inv); u1o.y = f2h_u(a11 * inv);
    ushort2 u2o; u2o.x = f2h_u(a20 * inv); u2o.y = f2h_u(a21 * inv);
    *(ushort2*)(agg1 + (size_t)node * C + lane * 2) = u1o;
    *(ushort2*)(agg2 + (size_t)node * C + lane * 2) = u2o;
}

// ---------------- MFMA GEMM (f16): C[n,128] = [A0|A1](n, 256) @ B(256,128) + bias ----------------
__global__ __launch_bounds__(256) void gemm_mfma(
    const unsigned short* __restrict__ A0, const unsigned short* __restrict__ A1,
    const unsigned short* __restrict__ Bt, const float* __restrict__ bias,
    float* __restrict__ Cout, unsigned short* __restrict__ Chf, int relu) {
    __shared__ __align__(16) unsigned short sA[128 * 136];
    __shared__ __align__(16) unsigned short sB[128 * 136];
    const int tx = threadIdx.x;
    const int l = tx & 63;
    const int wv = tx >> 6;
    const int wm = wv >> 1, wn = wv & 1;
    const int lr = l & 15;
    const int lq = l >> 4;
    const int n0 = blockIdx.x * 128;

    f32x4 acc[4][4] = {};
    for (int c = 0; c < 2; ++c) {
        const unsigned short* Ac = (c == 0) ? A0 : A1;
#pragma unroll
        for (int it = 0; it < 8; ++it) {
            int idx = it * 256 + tx;
            int r = idx >> 4, s = idx & 15;
            int n = n0 + r; n = n < NN ? n : NN - 1;
            *(short8_t*)(sA + r * 136 + s * 8) = *(const short8_t*)(Ac + (size_t)n * 128 + s * 8);
            *(short8_t*)(sB + r * 136 + s * 8) = *(const short8_t*)(Bt + c * 16384 + idx * 8);
        }
        __syncthreads();
#pragma unroll
        for (int ks = 0; ks < 4; ++ks) {
            half8_t af[4], bfr[4];
#pragma unroll
            for (int t = 0; t < 4; ++t) {
                af[t]  = *(const half8_t*)(sA + (wm * 64 + t * 16 + lr) * 136 + ks * 32 + lq * 8);
                bfr[t] = *(const half8_t*)(sB + (wn * 64 + t * 16 + lr) * 136 + ks * 32 + lq * 8);
            }
#pragma unroll
            for (int mt = 0; mt < 4; ++mt)
#pragma unroll
                for (int nt = 0; nt < 4; ++nt)
                    acc[mt][nt] = __builtin_amdgcn_mfma_f32_16x16x32_f16(af[mt], bfr[nt], acc[mt][nt], 0, 0, 0);
        }
        __syncthreads();
    }
#pragma unroll
    for (int mt = 0; mt < 4; ++mt) {
        int rbase = wm * 64 + mt * 16 + lq * 4;
#pragma unroll
        for (int nt = 0; nt < 4; ++nt) {
            int col = wn * 64 + nt * 16 + lr;
            float bv = bias[col];
#pragma unroll
            for (int rg = 0; rg < 4; ++rg) {
                int n = n0 + rbase + rg;
                if (n < NN) {
                    float y = acc[mt][nt][rg] + bv;
                    if (relu) y = fmaxf(y, 0.f);
                    if (Cout) Cout[(size_t)n * 128 + col] = y;
                    if (Chf) Chf[(size_t)n * 128 + col] = f2h_u(y);
                }
            }
        }
    }
}

// ---------------- attention scores via MFMA (f16) ----------------
__global__ __launch_bounds__(256) void att_score(
    const unsigned short* __restrict__ x1h, const unsigned short* __restrict__ x2h,
    const unsigned short* __restrict__ x3h, const unsigned short* __restrict__ x4h,
    const unsigned short* __restrict__ BtA, const float* __restrict__ b1,
    const float* __restrict__ W2, float* __restrict__ wout) {
    __shared__ __align__(16) unsigned short sA[128 * 136];
    __shared__ __align__(16) unsigned short sB[64 * 136];
    const int tx = threadIdx.x;
    const int n0 = blockIdx.x * 32;
    const unsigned short* zb[4] = {x1h, x2h, x3h, x4h};
#pragma unroll
    for (int it = 0; it < 8; ++it) {
        int idx = it * 256 + tx;
        int r = idx >> 4, s = idx & 15;
        int node = n0 + (r >> 2); node = node < NN ? node : NN - 1;
        *(short8_t*)(sA + r * 136 + s * 8) = *(const short8_t*)(zb[r & 3] + (size_t)node * 128 + s * 8);
    }
#pragma unroll
    for (int it = 0; it < 4; ++it) {
        int idx = it * 256 + tx;
        int r = idx >> 4, s = idx & 15;
        *(short8_t*)(sB + r * 136 + s * 8) = *(const short8_t*)(BtA + idx * 8);
    }
    __syncthreads();
    const int w = tx >> 6, lane = tx & 63, lr = lane & 15, lq = lane >> 4;
    f32x4 acc[2][4] = {};
#pragma unroll
    for (int ks = 0; ks < 4; ++ks) {
        half8_t af[2], bfr[4];
#pragma unroll
        for (int mt = 0; mt < 2; ++mt)
            af[mt] = *(const half8_t*)(sA + (w * 32 + mt * 16 + lr) * 136 + ks * 32 + lq * 8);
#pragma unroll
        for (int nt = 0; nt < 4; ++nt)
            bfr[nt] = *(const half8_t*)(sB + (nt * 16 + lr) * 136 + ks * 32 + lq * 8);
#pragma unroll
        for (int mt = 0; mt < 2; ++mt)
#pragma unroll
            for (int nt = 0; nt < 4; ++nt)
                acc[mt][nt] = __builtin_amdgcn_mfma_f32_16x16x32_f16(af[mt], bfr[nt], acc[mt][nt], 0, 0, 0);
    }
#pragma unroll
    for (int mt = 0; mt < 2; ++mt) {
        float part[4] = {0.f, 0.f, 0.f, 0.f};
#pragma unroll
        for (int nt = 0; nt < 4; ++nt) {
            int col = nt * 16 + lr;
            float bb = b1[col], w2 = W2[col];
#pragma unroll
            for (int rg = 0; rg < 4; ++rg) {
                float h = acc[mt][nt][rg] + bb;
                float cl = fminf(fmaxf(h, -15.f), 15.f);
                float e2 = __expf(2.f * cl);
                part[rg] += (e2 - 1.f) / (e2 + 1.f) * w2;
            }
        }
#pragma unroll
        for (int rg = 0; rg < 4; ++rg)
#pragma unroll
            for (int off = 1; off < 16; off <<= 1)
                part[rg] += __shfl_xor(part[rg], off, 64);
        if (lr == 0) {
#pragma unroll
            for (int rg = 0; rg < 4; ++rg) {
                int r = w * 32 + mt * 16 + lq * 4 + rg;
                int node = n0 + (r >> 2);
                if (node < NN) wout[(size_t)node * 4 + (r & 3)] = part[rg];
            }
        }
    }
}

// ---------------- softmax + weighted combine ----------------
__global__ __launch_bounds__(256) void att_combine(
    const float* __restrict__ x1, const unsigned short* __restrict__ x2h,
    const float* __restrict__ x3, const float* __restrict__ x4,
    const float* __restrict__ wsc, float* __restrict__ emb) {
    int node = blockIdx.x * 4 + (threadIdx.x >> 6);
    int lane = threadIdx.x & 63;
    float4 w = *(const float4*)(wsc + (size_t)node * 4);
    float m = fmaxf(fmaxf(w.x, w.y), fmaxf(w.z, w.w));
    float e0 = __expf(w.x - m), e1 = __expf(w.y - m), e2 = __expf(w.z - m), e3 = __expf(w.w - m);
    float inv = 1.f / (e0 + e1 + e2 + e3);
    float b0 = e0 * inv, b1 = e1 * inv, b2 = e2 * inv, b3 = e3 * inv;
    size_t base = (size_t)node * C + lane * 2;
    float2 z1 = *(const float2*)(x1 + base);
    half2_t u2 = *(const half2_t*)(x2h + base);
    float2 z3 = *(const float2*)(x3 + base);
    float2 z4 = *(const float2*)(x4 + base);
    float2 o;
    o.x = b0 * z1.x + b1 * (float)u2.x + b2 * z3.x + b3 * z4.x;
    o.y = b0 * z1.y + b1 * (float)u2.y + b2 * z3.y + b3 * z4.y;
    *(float2*)(emb + base) = o;
}

extern "C" void kernel_launch(void* const* d_in, const int* in_sizes, int n_in,
                              void* d_out, int out_size, void* d_ws, size_t ws_size,
                              hipStream_t stream) {
    const float* x   = (const float*)d_in[0];
    const int* row   = (const int*)d_in[1];
    const int* col   = (const int*)d_in[2];
    const float* Wl0 = (const float*)d_in[3];
    const float* bl0 = (const float*)d_in[4];
    const float* Wr0 = (const float*)d_in[5];
    const float* Wl1 = (const float*)d_in[6];
    const float* bl1 = (const float*)d_in[7];
    const float* Wr1 = (const float*)d_in[8];
    const float* aW1 = (const float*)d_in[9];
    const float* ab1 = (const float*)d_in[10];
    const float* aW2 = (const float*)d_in[11];

    float* out = (float*)d_out;
    float* emb = out;                         // x1 fp32 lives here until att_combine overwrites
    float* x3  = out + (size_t)NN * C;
    float* x4  = out + 2 * (size_t)NN * C;

    char* ws = (char*)d_ws;
    size_t off = 0;
    auto alloc = [&](size_t bytes) -> void* {
        void* p = ws + off;
        off += (bytes + 255) & ~(size_t)255;
        return p;
    };
    int* deg     = (int*)alloc((size_t)NN * 4);
    int* offsets = (int*)alloc((size_t)(NN + 1) * 4);
    int* cursor  = (int*)alloc((size_t)NN * 4);
    int* bsum    = (int*)alloc((size_t)64 * 4);
    int* colv    = (int*)alloc((size_t)NE * 4);
    float2* st1  = (float2*)alloc((size_t)NN * 8);
    float4* st2  = (float4*)alloc((size_t)NN * 16);
    unsigned short* xh    = (unsigned short*)alloc((size_t)NN * C * 2);  // reused as x1h
    unsigned short* aggch = (unsigned short*)alloc((size_t)NN * C * 2);  // reused: agg1
    unsigned short* aggeh = (unsigned short*)alloc((size_t)NN * C * 2);  // reused: agg2
    unsigned short* x3h   = (unsigned short*)alloc((size_t)NN * C * 2);
    unsigned short* x4h   = (unsigned short*)alloc((size_t)NN * C * 2);
    unsigned short* x2h   = (unsigned short*)alloc((size_t)NN * C * 2);
    unsigned short* Bt    = (unsigned short*)alloc((size_t)65536 * 2);
    unsigned short* BtA   = (unsigned short*)alloc((size_t)8192 * 2);
    float* wout  = (float*)alloc((size_t)NN * 4 * 4);

    hipMemsetAsync(deg, 0, (size_t)NN * 4, stream);
    count_deg<<<(NE + 255) / 256, 256, 0, stream>>>(row, deg);
    deg_block_sums<<<SCAN_NB, 256, 0, stream>>>(deg, bsum);
    scan_bsums<<<1, 64, 0, stream>>>(bsum);
    scan_within<<<SCAN_NB, 256, 0, stream>>>(deg, bsum, offsets, cursor);
    bucket_edges<<<(NE + 255) / 256, 256, 0, stream>>>(row, col, cursor, colv);

    cast_stats<<<NN / 4, 256, 0, stream>>>(x, xh, st1);
    prep_weights<<<(65536 + 8192) / 256, 256, 0, stream>>>(Wl0, Wr0, Wl1, Wr1, aW1, Bt, BtA);

    fused_l1<<<NN / 4, 256, 0, stream>>>(xh, colv, offsets, st1, aggch, aggeh);

    const int GB = (NN + 127) / 128;
    gemm_mfma<<<GB, 256, 0, stream>>>(aggch, xh, Bt, bl0, x3, x3h, 1);
    gemm_mfma<<<GB, 256, 0, stream>>>(aggeh, xh, Bt, bl0, x4, x4h, 1);

    stats2<<<NN / 4, 256, 0, stream>>>(x3, x4, st2);
    fused_l2<<<NN / 4, 256, 0, stream>>>(x3h, x4h, colv, offsets, st2, aggch, aggeh);

    gemm_mfma<<<GB, 256, 0, stream>>>(aggch, x3h, Bt + 32768, bl1, emb, xh /*x1h*/, 0);
    gemm_mfma<<<GB, 256, 0, stream>>>(aggeh, x4h, Bt + 32768, bl1, nullptr, x2h, 0);

    att_score<<<(NN + 31) / 32, 256, 0, stream>>>(xh, x2h, x3h, x4h, BtA, ab1, aW2, wout);
    att_combine<<<NN / 4, 256, 0, stream>>>(emb, x2h, x3, x4, wout, emb);
}

// Round 2
// 442.019 us; speedup vs baseline: 1.2230x; 1.2225x over previous
//
#include <hip/hip_runtime.h>

#define NN 50000
#define NE 800000
#define C 128

typedef __attribute__((ext_vector_type(8))) short short8_t;
typedef __attribute__((ext_vector_type(4))) float f32x4;
typedef __attribute__((ext_vector_type(2))) _Float16 half2_t;
typedef __attribute__((ext_vector_type(8))) _Float16 half8_t;

__device__ __forceinline__ unsigned short f2h_u(float f) {
    _Float16 h = (_Float16)f;
    union { _Float16 h; unsigned short u; } v; v.h = h; return v.u;
}

__device__ __forceinline__ float fdot2(half2_t a, half2_t b, float c) {
#if __has_builtin(__builtin_amdgcn_fdot2)
    return __builtin_amdgcn_fdot2(a, b, c, false);
#else
    return c + (float)a.x * (float)b.x + (float)a.y * (float)b.y;
#endif
}

// ---------------- CSR build ----------------
__global__ void count_deg(const int* __restrict__ row, int* __restrict__ deg) {
    int e = blockIdx.x * blockDim.x + threadIdx.x;
    if (e < NE) atomicAdd(&deg[row[e]], 1);
}

#define SCAN_NB ((NN + 1023) / 1024)

__global__ void deg_block_sums(const int* __restrict__ deg, int* __restrict__ bsum) {
    __shared__ int sred[256];
    int t = threadIdx.x;
    int base = blockIdx.x * 1024 + t * 4;
    int s = 0;
    if (base + 3 < NN) {
        int4 v = *(const int4*)(deg + base);
        s = v.x + v.y + v.z + v.w;
    } else {
        for (int i = 0; i < 4; ++i) if (base + i < NN) s += deg[base + i];
    }
    sred[t] = s; __syncthreads();
    for (int off = 128; off > 0; off >>= 1) {
        if (t < off) sred[t] += sred[t + off];
        __syncthreads();
    }
    if (t == 0) bsum[blockIdx.x] = sred[0];
}

__global__ void scan_bsums(int* __restrict__ bsum) {   // 1 block x 64
    int t = threadIdx.x;
    int v = (t < SCAN_NB) ? bsum[t] : 0;
#pragma unroll
    for (int off = 1; off < 64; off <<= 1) {
        int u = __shfl_up(v, off, 64);
        if (t >= off) v += u;
    }
    int ex = __shfl_up(v, 1, 64);
    if (t == 0) ex = 0;
    if (t < SCAN_NB) bsum[t] = ex;
}

__global__ void scan_within(const int* __restrict__ deg, const int* __restrict__ bsum,
                            int* __restrict__ offsets, int* __restrict__ cursor) {
    __shared__ int sdat[256];
    int t = threadIdx.x;
    int base = blockIdx.x * 1024 + t * 4;
    int d[4] = {0, 0, 0, 0};
    if (base + 3 < NN) {
        int4 v = *(const int4*)(deg + base);
        d[0] = v.x; d[1] = v.y; d[2] = v.z; d[3] = v.w;
    } else {
        for (int i = 0; i < 4; ++i) if (base + i < NN) d[i] = deg[base + i];
    }
    sdat[t] = d[0] + d[1] + d[2] + d[3];
    __syncthreads();
    for (int off = 1; off < 256; off <<= 1) {
        int v = sdat[t];
        int add = (t >= off) ? sdat[t - off] : 0;
        __syncthreads();
        sdat[t] = v + add;
        __syncthreads();
    }
    int run = bsum[blockIdx.x] + ((t == 0) ? 0 : sdat[t - 1]);
    for (int i = 0; i < 4; ++i) {
        int idx = base + i;
        if (idx < NN) { offsets[idx] = run; cursor[idx] = run; run += d[i]; }
    }
    if (blockIdx.x == 0 && t == 0) offsets[NN] = NE;
}

__global__ void bucket_edges(const int* __restrict__ row, const int* __restrict__ col,
                             int* __restrict__ cursor, int* __restrict__ colv) {
    int e = blockIdx.x * blockDim.x + threadIdx.x;
    if (e < NE) {
        int r = row[e];
        int p = atomicAdd(&cursor[r], 1);
        colv[p] = col[e];
    }
}

// ---------------- cast x -> fp16 AND per-node stats (packed float2) ----------------
__global__ void cast_stats(const float* __restrict__ x, unsigned short* __restrict__ xh,
                           float2* __restrict__ st1) {
    int node = blockIdx.x * 4 + (threadIdx.x >> 6);
    int lane = threadIdx.x & 63;
    float2 v = *(const float2*)(x + (size_t)node * C + lane * 2);
    half2_t h; h.x = (_Float16)v.x; h.y = (_Float16)v.y;
    *(half2_t*)(xh + (size_t)node * C + lane * 2) = h;
    float sq = v.x * v.x + v.y * v.y;
    float sm = v.x + v.y;
#pragma unroll
    for (int off = 32; off > 0; off >>= 1) {
        sq += __shfl_xor(sq, off, 64);
        sm += __shfl_xor(sm, off, 64);
    }
    if (lane == 0) st1[node] = make_float2(sq, sm);
}

// ---------------- layer-2 stats (packed float4: n2_3, n2_4, s1_4) ----------------
__global__ void stats2(const float* __restrict__ x3, const float* __restrict__ x4,
                       float4* __restrict__ st2) {
    int node = blockIdx.x * 4 + (threadIdx.x >> 6);
    int lane = threadIdx.x & 63;
    float2 a = *(const float2*)(x3 + (size_t)node * C + lane * 2);
    float2 b = *(const float2*)(x4 + (size_t)node * C + lane * 2);
    float q3 = a.x * a.x + a.y * a.y;
    float q4 = b.x * b.x + b.y * b.y;
    float m4 = b.x + b.y;
#pragma unroll
    for (int off = 32; off > 0; off >>= 1) {
        q3 += __shfl_xor(q3, off, 64);
        q4 += __shfl_xor(q4, off, 64);
        m4 += __shfl_xor(m4, off, 64);
    }
    if (lane == 0) st2[node] = make_float4(q3, q4, m4, 0.f);
}

// ---------------- weight prep (GEMM weights + attention W1), fused ----------------
__global__ void prep_weights(const float* __restrict__ Wl0, const float* __restrict__ Wr0,
                             const float* __restrict__ Wl1, const float* __restrict__ Wr1,
                             const float* __restrict__ aW1,
                             unsigned short* __restrict__ Bt, unsigned short* __restrict__ BtA) {
    int id = blockIdx.x * 256 + threadIdx.x;   // [0, 65536+8192)
    if (id < 65536) {
        int layer = id >> 15;
        int c = (id >> 14) & 1;
        int n = (id >> 7) & 127;
        int kk = id & 127;
        const float* W = layer == 0 ? (c == 0 ? Wl0 : Wr0) : (c == 0 ? Wl1 : Wr1);
        Bt[id] = f2h_u(W[kk * 128 + n]);
    } else {
        int a = id - 65536;                    // [0, 8192)
        int col = a >> 7, k = a & 127;
        BtA[a] = f2h_u(aW1[k * 64 + col]);
    }
}

// ---------------- FUSED layer 1: sim + aggregate, quarter-wave per edge -------------
// Wave per node; each 16-lane quarter handles one edge (lane owns 8 channels).
// Dot reduce = 4 shfl levels inside the quarter; per-quarter fp32 accumulators
// merged once per node via xor-16/32.
__global__ __launch_bounds__(256) void fused_l1(
    const unsigned short* __restrict__ xh, const int* __restrict__ colv,
    const int* __restrict__ offsets, const float2* __restrict__ st1,
    unsigned short* __restrict__ aggc, unsigned short* __restrict__ agge) {
    int node = blockIdx.x * 4 + (threadIdx.x >> 6);
    int lane = threadIdx.x & 63;
    int q = lane >> 4, lq = lane & 15;
    int beg = offsets[node], end = offsets[node + 1];
    half8_t xr = *(const half8_t*)(xh + (size_t)node * C + lq * 8);
    float2 sr = st1[node];
    float n2r = sr.x, s1r = sr.y;
    float ac[8] = {0.f, 0.f, 0.f, 0.f, 0.f, 0.f, 0.f, 0.f};
    float ae[8] = {0.f, 0.f, 0.f, 0.f, 0.f, 0.f, 0.f, 0.f};
    for (int p = beg; p < end; p += 4) {
        int pe = p + q;
        bool valid = pe < end;
        int c0 = colv[valid ? pe : beg];
        half8_t u = *(const half8_t*)(xh + (size_t)c0 * C + lq * 8);
        float2 t0 = st1[c0];
        float d = 0.f;
#pragma unroll
        for (int i = 0; i < 4; ++i) {
            half2_t a; a.x = xr[2 * i]; a.y = xr[2 * i + 1];
            half2_t b; b.x = u[2 * i]; b.y = u[2 * i + 1];
            d = fdot2(a, b, d);
        }
#pragma unroll
        for (int off = 1; off < 16; off <<= 1) d += __shfl_xor(d, off, 64);
        float wc0 = d / fmaxf(sqrtf(n2r * t0.x), 1e-8f);
        float qq = n2r + t0.x - 2.f * d + 2e-6f * (s1r - t0.y) + 1.28e-10f;
        float we0 = sqrtf(fmaxf(qq, 0.f));
        if (!valid) { wc0 = 0.f; we0 = 0.f; }
#pragma unroll
        for (int i = 0; i < 8; ++i) {
            float uv = (float)u[i];
            ac[i] += wc0 * uv;
            ae[i] += we0 * uv;
        }
    }
#pragma unroll
    for (int i = 0; i < 8; ++i) {
        ac[i] += __shfl_xor(ac[i], 16, 64);
        ac[i] += __shfl_xor(ac[i], 32, 64);
        ae[i] += __shfl_xor(ae[i], 16, 64);
        ae[i] += __shfl_xor(ae[i], 32, 64);
    }
    if (q == 0) {
        float inv = 1.f / fmaxf((float)(end - beg), 1.f);
        half8_t hc, he;
#pragma unroll
        for (int i = 0; i < 8; ++i) {
            hc[i] = (_Float16)(ac[i] * inv);
            he[i] = (_Float16)(ae[i] * inv);
        }
        *(half8_t*)(aggc + (size_t)node * C + lq * 8) = hc;
        *(half8_t*)(agge + (size_t)node * C + lq * 8) = he;
    }
}

// ---------------- FUSED layer 2: sim + aggregate, cos over x3 / eud over x4 ---------
__global__ __launch_bounds__(256) void fused_l2(
    const unsigned short* __restrict__ x3h, const unsigned short* __restrict__ x4h,
    const int* __restrict__ colv, const int* __restrict__ offsets,
    const float4* __restrict__ st2,
    unsigned short* __restrict__ agg1, unsigned short* __restrict__ agg2) {
    int node = blockIdx.x * 4 + (threadIdx.x >> 6);
    int lane = threadIdx.x & 63;
    int q = lane >> 4, lq = lane & 15;
    int beg = offsets[node], end = offsets[node + 1];
    half8_t x3r = *(const half8_t*)(x3h + (size_t)node * C + lq * 8);
    half8_t x4r = *(const half8_t*)(x4h + (size_t)node * C + lq * 8);
    float4 sr = st2[node];   // (n2_3, n2_4, s1_4, -)
    float a1[8] = {0.f, 0.f, 0.f, 0.f, 0.f, 0.f, 0.f, 0.f};
    float a2[8] = {0.f, 0.f, 0.f, 0.f, 0.f, 0.f, 0.f, 0.f};
    for (int p = beg; p < end; p += 4) {
        int pe = p + q;
        bool valid = pe < end;
        int c0 = colv[valid ? pe : beg];
        half8_t u = *(const half8_t*)(x3h + (size_t)c0 * C + lq * 8);
        half8_t v = *(const half8_t*)(x4h + (size_t)c0 * C + lq * 8);
        float4 t0 = st2[c0];
        float d3 = 0.f, d4 = 0.f;
#pragma unroll
        for (int i = 0; i < 4; ++i) {
            half2_t a; a.x = x3r[2 * i]; a.y = x3r[2 * i + 1];
            half2_t b; b.x = u[2 * i]; b.y = u[2 * i + 1];
            d3 = fdot2(a, b, d3);
            half2_t e; e.x = x4r[2 * i]; e.y = x4r[2 * i + 1];
            half2_t f; f.x = v[2 * i]; f.y = v[2 * i + 1];
            d4 = fdot2(e, f, d4);
        }
#pragma unroll
        for (int off = 1; off < 16; off <<= 1) {
            d3 += __shfl_xor(d3, off, 64);
            d4 += __shfl_xor(d4, off, 64);
        }
        float wc0 = d3 / fmaxf(sqrtf(sr.x * t0.x), 1e-8f);
        float qq = sr.y + t0.y - 2.f * d4 + 2e-6f * (sr.z - t0.z) + 1.28e-10f;
        float we0 = sqrtf(fmaxf(qq, 0.f));
        if (!valid) { wc0 = 0.f; we0 = 0.f; }
#pragma unroll
        for (int i = 0; i < 8; ++i) {
            a1[i] += wc0 * (float)u[i];
            a2[i] += we0 * (float)v[i];
        }
    }
#pragma unroll
    for (int i = 0; i < 8; ++i) {
        a1[i] += __shfl_xor(a1[i], 16, 64);
        a1[i] += __shfl_xor(a1[i], 32, 64);
        a2[i] += __shfl_xor(a2[i], 16, 64);
        a2[i] += __shfl_xor(a2[i], 32, 64);
    }
    if (q == 0) {
        float inv = 1.f / fmaxf((float)(end - beg), 1.f);
        half8_t h1, h2;
#pragma unroll
        for (int i = 0; i < 8; ++i) {
            h1[i] = (_Float16)(a1[i] * inv);
            h2[i] = (_Float16)(a2[i] * inv);
        }
        *(half8_t*)(agg1 + (size_t)node * C + lq * 8) = h1;
        *(half8_t*)(agg2 + (size_t)node * C + lq * 8) = h2;
    }
}

// ---------------- MFMA GEMM (f16): C[n,128] = [A0|A1](n, 256) @ B(256,128) + bias ----------------
__global__ __launch_bounds__(256) void gemm_mfma(
    const unsigned short* __restrict__ A0, const unsigned short* __restrict__ A1,
    const unsigned short* __restrict__ Bt, const float* __restrict__ bias,
    float* __restrict__ Cout, unsigned short* __restrict__ Chf, int relu) {
    __shared__ __align__(16) unsigned short sA[128 * 136];
    __shared__ __align__(16) unsigned short sB[128 * 136];
    const int tx = threadIdx.x;
    const int l = tx & 63;
    const int wv = tx >> 6;
    const int wm = wv >> 1, wn = wv & 1;
    const int lr = l & 15;
    const int lq = l >> 4;
    const int n0 = blockIdx.x * 128;

    f32x4 acc[4][4] = {};
    for (int c = 0; c < 2; ++c) {
        const unsigned short* Ac = (c == 0) ? A0 : A1;
#pragma unroll
        for (int it = 0; it < 8; ++it) {
            int idx = it * 256 + tx;
            int r = idx >> 4, s = idx & 15;
            int n = n0 + r; n = n < NN ? n : NN - 1;
            *(short8_t*)(sA + r * 136 + s * 8) = *(const short8_t*)(Ac + (size_t)n * 128 + s * 8);
            *(short8_t*)(sB + r * 136 + s * 8) = *(const short8_t*)(Bt + c * 16384 + idx * 8);
        }
        __syncthreads();
#pragma unroll
        for (int ks = 0; ks < 4; ++ks) {
            half8_t af[4], bfr[4];
#pragma unroll
            for (int t = 0; t < 4; ++t) {
                af[t]  = *(const half8_t*)(sA + (wm * 64 + t * 16 + lr) * 136 + ks * 32 + lq * 8);
                bfr[t] = *(const half8_t*)(sB + (wn * 64 + t * 16 + lr) * 136 + ks * 32 + lq * 8);
            }
#pragma unroll
            for (int mt = 0; mt < 4; ++mt)
#pragma unroll
                for (int nt = 0; nt < 4; ++nt)
                    acc[mt][nt] = __builtin_amdgcn_mfma_f32_16x16x32_f16(af[mt], bfr[nt], acc[mt][nt], 0, 0, 0);
        }
        __syncthreads();
    }
#pragma unroll
    for (int mt = 0; mt < 4; ++mt) {
        int rbase = wm * 64 + mt * 16 + lq * 4;
#pragma unroll
        for (int nt = 0; nt < 4; ++nt) {
            int col = wn * 64 + nt * 16 + lr;
            float bv = bias[col];
#pragma unroll
            for (int rg = 0; rg < 4; ++rg) {
                int n = n0 + rbase + rg;
                if (n < NN) {
                    float y = acc[mt][nt][rg] + bv;
                    if (relu) y = fmaxf(y, 0.f);
                    if (Cout) Cout[(size_t)n * 128 + col] = y;
                    if (Chf) Chf[(size_t)n * 128 + col] = f2h_u(y);
                }
            }
        }
    }
}

// ---------------- attention scores via MFMA (f16) ----------------
__global__ __launch_bounds__(256) void att_score(
    const unsigned short* __restrict__ x1h, const unsigned short* __restrict__ x2h,
    const unsigned short* __restrict__ x3h, const unsigned short* __restrict__ x4h,
    const unsigned short* __restrict__ BtA, const float* __restrict__ b1,
    const float* __restrict__ W2, float* __restrict__ wout) {
    __shared__ __align__(16) unsigned short sA[128 * 136];
    __shared__ __align__(16) unsigned short sB[64 * 136];
    const int tx = threadIdx.x;
    const int n0 = blockIdx.x * 32;
    const unsigned short* zb[4] = {x1h, x2h, x3h, x4h};
#pragma unroll
    for (int it = 0; it < 8; ++it) {
        int idx = it * 256 + tx;
        int r = idx >> 4, s = idx & 15;
        int node = n0 + (r >> 2); node = node < NN ? node : NN - 1;
        *(short8_t*)(sA + r * 136 + s * 8) = *(const short8_t*)(zb[r & 3] + (size_t)node * 128 + s * 8);
    }
#pragma unroll
    for (int it = 0; it < 4; ++it) {
        int idx = it * 256 + tx;
        int r = idx >> 4, s = idx & 15;
        *(short8_t*)(sB + r * 136 + s * 8) = *(const short8_t*)(BtA + idx * 8);
    }
    __syncthreads();
    const int w = tx >> 6, lane = tx & 63, lr = lane & 15, lq = lane >> 4;
    f32x4 acc[2][4] = {};
#pragma unroll
    for (int ks = 0; ks < 4; ++ks) {
        half8_t af[2], bfr[4];
#pragma unroll
        for (int mt = 0; mt < 2; ++mt)
            af[mt] = *(const half8_t*)(sA + (w * 32 + mt * 16 + lr) * 136 + ks * 32 + lq * 8);
#pragma unroll
        for (int nt = 0; nt < 4; ++nt)
            bfr[nt] = *(const half8_t*)(sB + (nt * 16 + lr) * 136 + ks * 32 + lq * 8);
#pragma unroll
        for (int mt = 0; mt < 2; ++mt)
#pragma unroll
            for (int nt = 0; nt < 4; ++nt)
                acc[mt][nt] = __builtin_amdgcn_mfma_f32_16x16x32_f16(af[mt], bfr[nt], acc[mt][nt], 0, 0, 0);
    }
#pragma unroll
    for (int mt = 0; mt < 2; ++mt) {
        float part[4] = {0.f, 0.f, 0.f, 0.f};
#pragma unroll
        for (int nt = 0; nt < 4; ++nt) {
            int col = nt * 16 + lr;
            float bb = b1[col], w2 = W2[col];
#pragma unroll
            for (int rg = 0; rg < 4; ++rg) {
                float h = acc[mt][nt][rg] + bb;
                float cl = fminf(fmaxf(h, -15.f), 15.f);
                float e2 = __expf(2.f * cl);
                part[rg] += (e2 - 1.f) / (e2 + 1.f) * w2;
            }
        }
#pragma unroll
        for (int rg = 0; rg < 4; ++rg)
#pragma unroll
            for (int off = 1; off < 16; off <<= 1)
                part[rg] += __shfl_xor(part[rg], off, 64);
        if (lr == 0) {
#pragma unroll
            for (int rg = 0; rg < 4; ++rg) {
                int r = w * 32 + mt * 16 + lq * 4 + rg;
                int node = n0 + (r >> 2);
                if (node < NN) wout[(size_t)node * 4 + (r & 3)] = part[rg];
            }
        }
    }
}

// ---------------- softmax + weighted combine ----------------
__global__ __launch_bounds__(256) void att_combine(
    const float* __restrict__ x1, const unsigned short* __restrict__ x2h,
    const float* __restrict__ x3, const float* __restrict__ x4,
    const float* __restrict__ wsc, float* __restrict__ emb) {
    int node = blockIdx.x * 4 + (threadIdx.x >> 6);
    int lane = threadIdx.x & 63;
    float4 w = *(const float4*)(wsc + (size_t)node * 4);
    float m = fmaxf(fmaxf(w.x, w.y), fmaxf(w.z, w.w));
    float e0 = __expf(w.x - m), e1 = __expf(w.y - m), e2 = __expf(w.z - m), e3 = __expf(w.w - m);
    float inv = 1.f / (e0 + e1 + e2 + e3);
    float b0 = e0 * inv, b1 = e1 * inv, b2 = e2 * inv, b3 = e3 * inv;
    size_t base = (size_t)node * C + lane * 2;
    float2 z1 = *(const float2*)(x1 + base);
    half2_t u2 = *(const half2_t*)(x2h + base);
    float2 z3 = *(const float2*)(x3 + base);
    float2 z4 = *(const float2*)(x4 + base);
    float2 o;
    o.x = b0 * z1.x + b1 * (float)u2.x + b2 * z3.x + b3 * z4.x;
    o.y = b0 * z1.y + b1 * (float)u2.y + b2 * z3.y + b3 * z4.y;
    *(float2*)(emb + base) = o;
}

extern "C" void kernel_launch(void* const* d_in, const int* in_sizes, int n_in,
                              void* d_out, int out_size, void* d_ws, size_t ws_size,
                              hipStream_t stream) {
    const float* x   = (const float*)d_in[0];
    const int* row   = (const int*)d_in[1];
    const int* col   = (const int*)d_in[2];
    const float* Wl0 = (const float*)d_in[3];
    const float* bl0 = (const float*)d_in[4];
    const float* Wr0 = (const float*)d_in[5];
    const float* Wl1 = (const float*)d_in[6];
    const float* bl1 = (const float*)d_in[7];
    const float* Wr1 = (const float*)d_in[8];
    const float* aW1 = (const float*)d_in[9];
    const float* ab1 = (const float*)d_in[10];
    const float* aW2 = (const float*)d_in[11];

    float* out = (float*)d_out;
    float* emb = out;                         // x1 fp32 lives here until att_combine overwrites
    float* x3  = out + (size_t)NN * C;
    float* x4  = out + 2 * (size_t)NN * C;

    char* ws = (char*)d_ws;
    size_t off = 0;
    auto alloc = [&](size_t bytes) -> void* {
        void* p = ws + off;
        off += (bytes + 255) & ~(size_t)255;
        return p;
    };
    int* deg     = (int*)alloc((size_t)NN * 4);
    int* offsets = (int*)alloc((size_t)(NN + 1) * 4);
    int* cursor  = (int*)alloc((size_t)NN * 4);
    int* bsum    = (int*)alloc((size_t)64 * 4);
    int* colv    = (int*)alloc((size_t)NE * 4);
    float2* st1  = (float2*)alloc((size_t)NN * 8);
    float4* st2  = (float4*)alloc((size_t)NN * 16);
    unsigned short* xh    = (unsigned short*)alloc((size_t)NN * C * 2);  // reused as x1h
    unsigned short* aggch = (unsigned short*)alloc((size_t)NN * C * 2);  // reused: agg1
    unsigned short* aggeh = (unsigned short*)alloc((size_t)NN * C * 2);  // reused: agg2
    unsigned short* x3h   = (unsigned short*)alloc((size_t)NN * C * 2);
    unsigned short* x4h   = (unsigned short*)alloc((size_t)NN * C * 2);
    unsigned short* x2h   = (unsigned short*)alloc((size_t)NN * C * 2);
    unsigned short* Bt    = (unsigned short*)alloc((size_t)65536 * 2);
    unsigned short* BtA   = (unsigned short*)alloc((size_t)8192 * 2);
    float* wout  = (float*)alloc((size_t)NN * 4 * 4);

    hipMemsetAsync(deg, 0, (size_t)NN * 4, stream);
    count_deg<<<(NE + 255) / 256, 256, 0, stream>>>(row, deg);
    deg_block_sums<<<SCAN_NB, 256, 0, stream>>>(deg, bsum);
    scan_bsums<<<1, 64, 0, stream>>>(bsum);
    scan_within<<<SCAN_NB, 256, 0, stream>>>(deg, bsum, offsets, cursor);
    bucket_edges<<<(NE + 255) / 256, 256, 0, stream>>>(row, col, cursor, colv);

    cast_stats<<<NN / 4, 256, 0, stream>>>(x, xh, st1);
    prep_weights<<<(65536 + 8192) / 256, 256, 0, stream>>>(Wl0, Wr0, Wl1, Wr1, aW1, Bt, BtA);

    fused_l1<<<NN / 4, 256, 0, stream>>>(xh, colv, offsets, st1, aggch, aggeh);

    const int GB = (NN + 127) / 128;
    gemm_mfma<<<GB, 256, 0, stream>>>(aggch, xh, Bt, bl0, x3, x3h, 1);
    gemm_mfma<<<GB, 256, 0, stream>>>(aggeh, xh, Bt, bl0, x4, x4h, 1);

    stats2<<<NN / 4, 256, 0, stream>>>(x3, x4, st2);
    fused_l2<<<NN / 4, 256, 0, stream>>>(x3h, x4h, colv, offsets, st2, aggch, aggeh);

    gemm_mfma<<<GB, 256, 0, stream>>>(aggch, x3h, Bt + 32768, bl1, emb, xh /*x1h*/, 0);
    gemm_mfma<<<GB, 256, 0, stream>>>(aggeh, x4h, Bt + 32768, bl1, nullptr, x2h, 0);

    att_score<<<(NN + 31) / 32, 256, 0, stream>>>(xh, x2h, x3h, x4h, BtA, ab1, aW2, wout);
    att_combine<<<NN / 4, 256, 0, stream>>>(emb, x2h, x3, x4, wout, emb);
}

// Round 3
// 413.070 us; speedup vs baseline: 1.3087x; 1.0701x over previous
//
#include <hip/hip_runtime.h>

#define NN 50000
#define NE 800000
#define C 128

typedef __attribute__((ext_vector_type(8))) short short8_t;
typedef __attribute__((ext_vector_type(4))) float f32x4;
typedef __attribute__((ext_vector_type(2))) _Float16 half2_t;
typedef __attribute__((ext_vector_type(8))) _Float16 half8_t;

__device__ __forceinline__ unsigned short f2h_u(float f) {
    _Float16 h = (_Float16)f;
    union { _Float16 h; unsigned short u; } v; v.h = h; return v.u;
}

__device__ __forceinline__ float fdot2(half2_t a, half2_t b, float c) {
#if __has_builtin(__builtin_amdgcn_fdot2)
    return __builtin_amdgcn_fdot2(a, b, c, false);
#else
    return c + (float)a.x * (float)b.x + (float)a.y * (float)b.y;
#endif
}

// ---------------- CSR build ----------------
__global__ void count_deg(const int* __restrict__ row, int* __restrict__ deg) {
    int e = blockIdx.x * blockDim.x + threadIdx.x;
    if (e < NE) atomicAdd(&deg[row[e]], 1);
}

#define SCAN_NB ((NN + 1023) / 1024)

__global__ void deg_block_sums(const int* __restrict__ deg, int* __restrict__ bsum) {
    __shared__ int sred[256];
    int t = threadIdx.x;
    int base = blockIdx.x * 1024 + t * 4;
    int s = 0;
    if (base + 3 < NN) {
        int4 v = *(const int4*)(deg + base);
        s = v.x + v.y + v.z + v.w;
    } else {
        for (int i = 0; i < 4; ++i) if (base + i < NN) s += deg[base + i];
    }
    sred[t] = s; __syncthreads();
    for (int off = 128; off > 0; off >>= 1) {
        if (t < off) sred[t] += sred[t + off];
        __syncthreads();
    }
    if (t == 0) bsum[blockIdx.x] = sred[0];
}

__global__ void scan_bsums(int* __restrict__ bsum) {   // 1 block x 64
    int t = threadIdx.x;
    int v = (t < SCAN_NB) ? bsum[t] : 0;
#pragma unroll
    for (int off = 1; off < 64; off <<= 1) {
        int u = __shfl_up(v, off, 64);
        if (t >= off) v += u;
    }
    int ex = __shfl_up(v, 1, 64);
    if (t == 0) ex = 0;
    if (t < SCAN_NB) bsum[t] = ex;
}

__global__ void scan_within(const int* __restrict__ deg, const int* __restrict__ bsum,
                            int* __restrict__ offsets, int* __restrict__ cursor) {
    __shared__ int sdat[256];
    int t = threadIdx.x;
    int base = blockIdx.x * 1024 + t * 4;
    int d[4] = {0, 0, 0, 0};
    if (base + 3 < NN) {
        int4 v = *(const int4*)(deg + base);
        d[0] = v.x; d[1] = v.y; d[2] = v.z; d[3] = v.w;
    } else {
        for (int i = 0; i < 4; ++i) if (base + i < NN) d[i] = deg[base + i];
    }
    sdat[t] = d[0] + d[1] + d[2] + d[3];
    __syncthreads();
    for (int off = 1; off < 256; off <<= 1) {
        int v = sdat[t];
        int add = (t >= off) ? sdat[t - off] : 0;
        __syncthreads();
        sdat[t] = v + add;
        __syncthreads();
    }
    int run = bsum[blockIdx.x] + ((t == 0) ? 0 : sdat[t - 1]);
    for (int i = 0; i < 4; ++i) {
        int idx = base + i;
        if (idx < NN) { offsets[idx] = run; cursor[idx] = run; run += d[i]; }
    }
    if (blockIdx.x == 0 && t == 0) offsets[NN] = NE;
}

__global__ void bucket_edges(const int* __restrict__ row, const int* __restrict__ col,
                             int* __restrict__ cursor, int* __restrict__ colv) {
    int e = blockIdx.x * blockDim.x + threadIdx.x;
    if (e < NE) {
        int r = row[e];
        int p = atomicAdd(&cursor[r], 1);
        colv[p] = col[e];
    }
}

// ---------------- fused: cast x -> fp16 + per-node stats  AND  weight prep ----------
#define CAST_NB (NN / 4)
__global__ void cast_prep(const float* __restrict__ x, unsigned short* __restrict__ xh,
                          float2* __restrict__ st1,
                          const float* __restrict__ Wl0, const float* __restrict__ Wr0,
                          const float* __restrict__ Wl1, const float* __restrict__ Wr1,
                          const float* __restrict__ aW1,
                          unsigned short* __restrict__ Bt, unsigned short* __restrict__ BtA) {
    if (blockIdx.x < CAST_NB) {
        int node = blockIdx.x * 4 + (threadIdx.x >> 6);
        int lane = threadIdx.x & 63;
        float2 v = *(const float2*)(x + (size_t)node * C + lane * 2);
        half2_t h; h.x = (_Float16)v.x; h.y = (_Float16)v.y;
        *(half2_t*)(xh + (size_t)node * C + lane * 2) = h;
        float sq = v.x * v.x + v.y * v.y;
        float sm = v.x + v.y;
#pragma unroll
        for (int off = 32; off > 0; off >>= 1) {
            sq += __shfl_xor(sq, off, 64);
            sm += __shfl_xor(sm, off, 64);
        }
        if (lane == 0) st1[node] = make_float2(sq, sm);
    } else {
        int id = (blockIdx.x - CAST_NB) * 256 + threadIdx.x;   // [0, 65536+8192)
        if (id < 65536) {
            int layer = id >> 15;
            int c = (id >> 14) & 1;
            int n = (id >> 7) & 127;
            int kk = id & 127;
            const float* W = layer == 0 ? (c == 0 ? Wl0 : Wr0) : (c == 0 ? Wl1 : Wr1);
            Bt[id] = f2h_u(W[kk * 128 + n]);
        } else {
            int a = id - 65536;                    // [0, 8192)
            int col = a >> 7, k = a & 127;
            BtA[a] = f2h_u(aW1[k * 64 + col]);
        }
    }
}

// ---------------- layer-2 stats from fp16 interleaved x34h -------------------------
__global__ void stats2h(const unsigned short* __restrict__ x34h, float4* __restrict__ st2) {
    int node = blockIdx.x * 4 + (threadIdx.x >> 6);
    int lane = threadIdx.x & 63;
    const unsigned short* base = x34h + (size_t)node * 256 + lane * 2;
    half2_t a = *(const half2_t*)(base);
    half2_t b = *(const half2_t*)(base + 128);
    float q3 = fdot2(a, a, 0.f);
    float q4 = fdot2(b, b, 0.f);
    float m4 = (float)b.x + (float)b.y;
#pragma unroll
    for (int off = 32; off > 0; off >>= 1) {
        q3 += __shfl_xor(q3, off, 64);
        q4 += __shfl_xor(q4, off, 64);
        m4 += __shfl_xor(m4, off, 64);
    }
    if (lane == 0) st2[node] = make_float4(q3, q4, m4, 0.f);
}

// ---------------- FUSED layer 1: sim + aggregate, quarter-wave per edge -------------
__global__ __launch_bounds__(256) void fused_l1(
    const unsigned short* __restrict__ xh, const int* __restrict__ colv,
    const int* __restrict__ offsets, const float2* __restrict__ st1,
    unsigned short* __restrict__ aggc, unsigned short* __restrict__ agge) {
    int node = blockIdx.x * 4 + (threadIdx.x >> 6);
    int lane = threadIdx.x & 63;
    int q = lane >> 4, lq = lane & 15;
    int beg = offsets[node], end = offsets[node + 1];
    half8_t xr = *(const half8_t*)(xh + (size_t)node * C + lq * 8);
    float2 sr = st1[node];
    float n2r = sr.x, s1r = sr.y;
    float ac[8] = {0.f, 0.f, 0.f, 0.f, 0.f, 0.f, 0.f, 0.f};
    float ae[8] = {0.f, 0.f, 0.f, 0.f, 0.f, 0.f, 0.f, 0.f};
    for (int p = beg; p < end; p += 4) {
        int pe = p + q;
        bool valid = pe < end;
        int c0 = colv[valid ? pe : beg];
        half8_t u = *(const half8_t*)(xh + (size_t)c0 * C + lq * 8);
        float2 t0 = st1[c0];
        float d = 0.f;
#pragma unroll
        for (int i = 0; i < 4; ++i) {
            half2_t a; a.x = xr[2 * i]; a.y = xr[2 * i + 1];
            half2_t b; b.x = u[2 * i]; b.y = u[2 * i + 1];
            d = fdot2(a, b, d);
        }
#pragma unroll
        for (int off = 1; off < 16; off <<= 1) d += __shfl_xor(d, off, 64);
        float wc0 = d / fmaxf(sqrtf(n2r * t0.x), 1e-8f);
        float qq = n2r + t0.x - 2.f * d + 2e-6f * (s1r - t0.y) + 1.28e-10f;
        float we0 = sqrtf(fmaxf(qq, 0.f));
        if (!valid) { wc0 = 0.f; we0 = 0.f; }
#pragma unroll
        for (int i = 0; i < 8; ++i) {
            float uv = (float)u[i];
            ac[i] += wc0 * uv;
            ae[i] += we0 * uv;
        }
    }
#pragma unroll
    for (int i = 0; i < 8; ++i) {
        ac[i] += __shfl_xor(ac[i], 16, 64);
        ac[i] += __shfl_xor(ac[i], 32, 64);
        ae[i] += __shfl_xor(ae[i], 16, 64);
        ae[i] += __shfl_xor(ae[i], 32, 64);
    }
    if (q == 0) {
        float inv = 1.f / fmaxf((float)(end - beg), 1.f);
        half8_t hc, he;
#pragma unroll
        for (int i = 0; i < 8; ++i) {
            hc[i] = (_Float16)(ac[i] * inv);
            he[i] = (_Float16)(ae[i] * inv);
        }
        *(half8_t*)(aggc + (size_t)node * C + lq * 8) = hc;
        *(half8_t*)(agge + (size_t)node * C + lq * 8) = he;
    }
}

// ---------------- FUSED layer 2: sim + aggregate over interleaved x34h --------------
__global__ __launch_bounds__(256) void fused_l2(
    const unsigned short* __restrict__ x34h,
    const int* __restrict__ colv, const int* __restrict__ offsets,
    const float4* __restrict__ st2,
    unsigned short* __restrict__ agg1, unsigned short* __restrict__ agg2) {
    int node = blockIdx.x * 4 + (threadIdx.x >> 6);
    int lane = threadIdx.x & 63;
    int q = lane >> 4, lq = lane & 15;
    int beg = offsets[node], end = offsets[node + 1];
    const unsigned short* nb = x34h + (size_t)node * 256 + lq * 8;
    half8_t x3r = *(const half8_t*)(nb);
    half8_t x4r = *(const half8_t*)(nb + 128);
    float4 sr = st2[node];   // (n2_3, n2_4, s1_4, -)
    float a1[8] = {0.f, 0.f, 0.f, 0.f, 0.f, 0.f, 0.f, 0.f};
    float a2[8] = {0.f, 0.f, 0.f, 0.f, 0.f, 0.f, 0.f, 0.f};
    for (int p = beg; p < end; p += 4) {
        int pe = p + q;
        bool valid = pe < end;
        int c0 = colv[valid ? pe : beg];
        const unsigned short* cb = x34h + (size_t)c0 * 256 + lq * 8;
        half8_t u = *(const half8_t*)(cb);
        half8_t v = *(const half8_t*)(cb + 128);
        float4 t0 = st2[c0];
        float d3 = 0.f, d4 = 0.f;
#pragma unroll
        for (int i = 0; i < 4; ++i) {
            half2_t a; a.x = x3r[2 * i]; a.y = x3r[2 * i + 1];
            half2_t b; b.x = u[2 * i]; b.y = u[2 * i + 1];
            d3 = fdot2(a, b, d3);
            half2_t e; e.x = x4r[2 * i]; e.y = x4r[2 * i + 1];
            half2_t f; f.x = v[2 * i]; f.y = v[2 * i + 1];
            d4 = fdot2(e, f, d4);
        }
#pragma unroll
        for (int off = 1; off < 16; off <<= 1) {
            d3 += __shfl_xor(d3, off, 64);
            d4 += __shfl_xor(d4, off, 64);
        }
        float wc0 = d3 / fmaxf(sqrtf(sr.x * t0.x), 1e-8f);
        float qq = sr.y + t0.y - 2.f * d4 + 2e-6f * (sr.z - t0.z) + 1.28e-10f;
        float we0 = sqrtf(fmaxf(qq, 0.f));
        if (!valid) { wc0 = 0.f; we0 = 0.f; }
#pragma unroll
        for (int i = 0; i < 8; ++i) {
            a1[i] += wc0 * (float)u[i];
            a2[i] += we0 * (float)v[i];
        }
    }
#pragma unroll
    for (int i = 0; i < 8; ++i) {
        a1[i] += __shfl_xor(a1[i], 16, 64);
        a1[i] += __shfl_xor(a1[i], 32, 64);
        a2[i] += __shfl_xor(a2[i], 16, 64);
        a2[i] += __shfl_xor(a2[i], 32, 64);
    }
    if (q == 0) {
        float inv = 1.f / fmaxf((float)(end - beg), 1.f);
        half8_t h1, h2;
#pragma unroll
        for (int i = 0; i < 8; ++i) {
            h1[i] = (_Float16)(a1[i] * inv);
            h2[i] = (_Float16)(a2[i] * inv);
        }
        *(half8_t*)(agg1 + (size_t)node * C + lq * 8) = h1;
        *(half8_t*)(agg2 + (size_t)node * C + lq * 8) = h2;
    }
}

// ---------------- dual-branch MFMA GEMM: both branches in one launch ----------------
// branch b = blockIdx.y. C[n,128] = [A0|A1](n,256) @ B(256,128) + bias.
__global__ __launch_bounds__(256) void gemm_dual(
    const unsigned short* __restrict__ A0a, const unsigned short* __restrict__ A0b,
    const unsigned short* __restrict__ A1a, const unsigned short* __restrict__ A1b,
    int a1stride,
    const unsigned short* __restrict__ Bt, const float* __restrict__ bias,
    float* __restrict__ Couta, float* __restrict__ Coutb,
    unsigned short* __restrict__ Chfa, unsigned short* __restrict__ Chfb,
    int chfstride, int relu) {
    __shared__ __align__(16) unsigned short sA[128 * 136];
    __shared__ __align__(16) unsigned short sB[128 * 136];
    const int br = blockIdx.y;
    const unsigned short* A0 = br ? A0b : A0a;
    const unsigned short* A1 = br ? A1b : A1a;
    float* Cout = br ? Coutb : Couta;
    unsigned short* Chf = br ? Chfb : Chfa;
    const int tx = threadIdx.x;
    const int l = tx & 63;
    const int wv = tx >> 6;
    const int wm = wv >> 1, wn = wv & 1;
    const int lr = l & 15;
    const int lq = l >> 4;
    const int n0 = blockIdx.x * 128;

    f32x4 acc[4][4] = {};
    for (int c = 0; c < 2; ++c) {
        const unsigned short* Ac = (c == 0) ? A0 : A1;
        const size_t strideA = (c == 0) ? 128 : a1stride;
#pragma unroll
        for (int it = 0; it < 8; ++it) {
            int idx = it * 256 + tx;
            int r = idx >> 4, s = idx & 15;
            int n = n0 + r; n = n < NN ? n : NN - 1;
            *(short8_t*)(sA + r * 136 + s * 8) = *(const short8_t*)(Ac + (size_t)n * strideA + s * 8);
            *(short8_t*)(sB + r * 136 + s * 8) = *(const short8_t*)(Bt + c * 16384 + idx * 8);
        }
        __syncthreads();
#pragma unroll
        for (int ks = 0; ks < 4; ++ks) {
            half8_t af[4], bfr[4];
#pragma unroll
            for (int t = 0; t < 4; ++t) {
                af[t]  = *(const half8_t*)(sA + (wm * 64 + t * 16 + lr) * 136 + ks * 32 + lq * 8);
                bfr[t] = *(const half8_t*)(sB + (wn * 64 + t * 16 + lr) * 136 + ks * 32 + lq * 8);
            }
#pragma unroll
            for (int mt = 0; mt < 4; ++mt)
#pragma unroll
                for (int nt = 0; nt < 4; ++nt)
                    acc[mt][nt] = __builtin_amdgcn_mfma_f32_16x16x32_f16(af[mt], bfr[nt], acc[mt][nt], 0, 0, 0);
        }
        __syncthreads();
    }
#pragma unroll
    for (int mt = 0; mt < 4; ++mt) {
        int rbase = wm * 64 + mt * 16 + lq * 4;
#pragma unroll
        for (int nt = 0; nt < 4; ++nt) {
            int col = wn * 64 + nt * 16 + lr;
            float bv = bias[col];
#pragma unroll
            for (int rg = 0; rg < 4; ++rg) {
                int n = n0 + rbase + rg;
                if (n < NN) {
                    float y = acc[mt][nt][rg] + bv;
                    if (relu) y = fmaxf(y, 0.f);
                    if (Cout) Cout[(size_t)n * 128 + col] = y;
                    Chf[(size_t)n * chfstride + col] = f2h_u(y);
                }
            }
        }
    }
}

// ---------------- fused attention: scores via MFMA + softmax + combine --------------
__global__ __launch_bounds__(256) void att_fused(
    const unsigned short* __restrict__ x12h, const unsigned short* __restrict__ x34h,
    const unsigned short* __restrict__ BtA, const float* __restrict__ b1,
    const float* __restrict__ W2, float* __restrict__ emb) {
    __shared__ __align__(16) unsigned short sA[128 * 136];
    __shared__ __align__(16) unsigned short sB[64 * 136];
    __shared__ float sW[32][4];
    const int tx = threadIdx.x;
    const int n0 = blockIdx.x * 32;
#pragma unroll
    for (int it = 0; it < 8; ++it) {
        int idx = it * 256 + tx;
        int r = idx >> 4, s = idx & 15;
        int node = n0 + (r >> 2); node = node < NN ? node : NN - 1;
        int b = r & 3;
        const unsigned short* src = (b < 2 ? x12h : x34h) + (size_t)node * 256 + (b & 1) * 128 + s * 8;
        *(short8_t*)(sA + r * 136 + s * 8) = *(const short8_t*)(src);
    }
#pragma unroll
    for (int it = 0; it < 4; ++it) {
        int idx = it * 256 + tx;
        int r = idx >> 4, s = idx & 15;
        *(short8_t*)(sB + r * 136 + s * 8) = *(const short8_t*)(BtA + idx * 8);
    }
    __syncthreads();
    const int w = tx >> 6, lane = tx & 63, lr = lane & 15, lq = lane >> 4;
    f32x4 acc[2][4] = {};
#pragma unroll
    for (int ks = 0; ks < 4; ++ks) {
        half8_t af[2], bfr[4];
#pragma unroll
        for (int mt = 0; mt < 2; ++mt)
            af[mt] = *(const half8_t*)(sA + (w * 32 + mt * 16 + lr) * 136 + ks * 32 + lq * 8);
#pragma unroll
        for (int nt = 0; nt < 4; ++nt)
            bfr[nt] = *(const half8_t*)(sB + (nt * 16 + lr) * 136 + ks * 32 + lq * 8);
#pragma unroll
        for (int mt = 0; mt < 2; ++mt)
#pragma unroll
            for (int nt = 0; nt < 4; ++nt)
                acc[mt][nt] = __builtin_amdgcn_mfma_f32_16x16x32_f16(af[mt], bfr[nt], acc[mt][nt], 0, 0, 0);
    }
#pragma unroll
    for (int mt = 0; mt < 2; ++mt) {
        float part[4] = {0.f, 0.f, 0.f, 0.f};
#pragma unroll
        for (int nt = 0; nt < 4; ++nt) {
            int col = nt * 16 + lr;
            float bb = b1[col], w2 = W2[col];
#pragma unroll
            for (int rg = 0; rg < 4; ++rg) {
                float h = acc[mt][nt][rg] + bb;
                float cl = fminf(fmaxf(h, -15.f), 15.f);
                float e2 = __expf(2.f * cl);
                part[rg] += (e2 - 1.f) / (e2 + 1.f) * w2;
            }
        }
#pragma unroll
        for (int rg = 0; rg < 4; ++rg)
#pragma unroll
            for (int off = 1; off < 16; off <<= 1)
                part[rg] += __shfl_xor(part[rg], off, 64);
        if (lr == 0) {
#pragma unroll
            for (int rg = 0; rg < 4; ++rg) {
                int r = w * 32 + mt * 16 + lq * 4 + rg;
                sW[r >> 2][r & 3] = part[rg];
            }
        }
    }
    __syncthreads();
    // combine: 8 threads per node, 16 channels each
    int ln = tx >> 3;
    int node = n0 + ln;
    if (node < NN) {
        int ch0 = (tx & 7) * 16;
        float w0 = sW[ln][0], w1 = sW[ln][1], w2 = sW[ln][2], w3 = sW[ln][3];
        float m = fmaxf(fmaxf(w0, w1), fmaxf(w2, w3));
        float e0 = __expf(w0 - m), e1 = __expf(w1 - m), e2 = __expf(w2 - m), e3 = __expf(w3 - m);
        float inv = 1.f / (e0 + e1 + e2 + e3);
        float bt[4] = {e0 * inv, e1 * inv, e2 * inv, e3 * inv};
        float o[16];
#pragma unroll
        for (int i = 0; i < 16; ++i) o[i] = 0.f;
#pragma unroll
        for (int b = 0; b < 4; ++b) {
            int rowoff = (ln * 4 + b) * 136 + ch0;
            half8_t h0 = *(const half8_t*)(sA + rowoff);
            half8_t h1 = *(const half8_t*)(sA + rowoff + 8);
            float bb = bt[b];
#pragma unroll
            for (int i = 0; i < 8; ++i) {
                o[i]     += bb * (float)h0[i];
                o[8 + i] += bb * (float)h1[i];
            }
        }
        float* dst = emb + (size_t)node * 128 + ch0;
#pragma unroll
        for (int i = 0; i < 4; ++i) {
            float4 v4; v4.x = o[4 * i]; v4.y = o[4 * i + 1]; v4.z = o[4 * i + 2]; v4.w = o[4 * i + 3];
            *(float4*)(dst + 4 * i) = v4;
        }
    }
}

extern "C" void kernel_launch(void* const* d_in, const int* in_sizes, int n_in,
                              void* d_out, int out_size, void* d_ws, size_t ws_size,
                              hipStream_t stream) {
    const float* x   = (const float*)d_in[0];
    const int* row   = (const int*)d_in[1];
    const int* col   = (const int*)d_in[2];
    const float* Wl0 = (const float*)d_in[3];
    const float* bl0 = (const float*)d_in[4];
    const float* Wr0 = (const float*)d_in[5];
    const float* Wl1 = (const float*)d_in[6];
    const float* bl1 = (const float*)d_in[7];
    const float* Wr1 = (const float*)d_in[8];
    const float* aW1 = (const float*)d_in[9];
    const float* ab1 = (const float*)d_in[10];
    const float* aW2 = (const float*)d_in[11];

    float* out = (float*)d_out;
    float* emb = out;
    float* x3  = out + (size_t)NN * C;
    float* x4  = out + 2 * (size_t)NN * C;

    char* ws = (char*)d_ws;
    size_t off = 0;
    auto alloc = [&](size_t bytes) -> void* {
        void* p = ws + off;
        off += (bytes + 255) & ~(size_t)255;
        return p;
    };
    int* deg     = (int*)alloc((size_t)NN * 4);
    int* offsets = (int*)alloc((size_t)(NN + 1) * 4);
    int* cursor  = (int*)alloc((size_t)NN * 4);
    int* bsum    = (int*)alloc((size_t)64 * 4);
    int* colv    = (int*)alloc((size_t)NE * 4);
    float2* st1  = (float2*)alloc((size_t)NN * 8);
    float4* st2  = (float4*)alloc((size_t)NN * 16);
    unsigned short* xh    = (unsigned short*)alloc((size_t)NN * C * 2);
    unsigned short* aggch = (unsigned short*)alloc((size_t)NN * C * 2);  // reused: agg1
    unsigned short* aggeh = (unsigned short*)alloc((size_t)NN * C * 2);  // reused: agg2
    unsigned short* x34h  = (unsigned short*)alloc((size_t)NN * 256 * 2); // interleaved x3h|x4h
    unsigned short* x12h  = (unsigned short*)alloc((size_t)NN * 256 * 2); // interleaved x1h|x2h
    unsigned short* Bt    = (unsigned short*)alloc((size_t)65536 * 2);
    unsigned short* BtA   = (unsigned short*)alloc((size_t)8192 * 2);

    hipMemsetAsync(deg, 0, (size_t)NN * 4, stream);
    count_deg<<<(NE + 255) / 256, 256, 0, stream>>>(row, deg);
    deg_block_sums<<<SCAN_NB, 256, 0, stream>>>(deg, bsum);
    scan_bsums<<<1, 64, 0, stream>>>(bsum);
    scan_within<<<SCAN_NB, 256, 0, stream>>>(deg, bsum, offsets, cursor);
    bucket_edges<<<(NE + 255) / 256, 256, 0, stream>>>(row, col, cursor, colv);

    cast_prep<<<CAST_NB + (65536 + 8192) / 256, 256, 0, stream>>>(
        x, xh, st1, Wl0, Wr0, Wl1, Wr1, aW1, Bt, BtA);

    fused_l1<<<NN / 4, 256, 0, stream>>>(xh, colv, offsets, st1, aggch, aggeh);

    const int GB = (NN + 127) / 128;
    // layer 1: both branches; writes x3/x4 fp32 + interleaved x34h fp16
    gemm_dual<<<dim3(GB, 2), 256, 0, stream>>>(
        aggch, aggeh, xh, xh, 128, Bt, bl0,
        x3, x4, x34h, x34h + 128, 256, 1);

    stats2h<<<NN / 4, 256, 0, stream>>>(x34h, st2);
    fused_l2<<<NN / 4, 256, 0, stream>>>(x34h, colv, offsets, st2, aggch, aggeh);

    // layer 2: both branches; fp16-only interleaved x12h
    gemm_dual<<<dim3(GB, 2), 256, 0, stream>>>(
        aggch, aggeh, x34h, x34h + 128, 256, Bt + 32768, bl1,
        nullptr, nullptr, x12h, x12h + 128, 256, 0);

    att_fused<<<(NN + 31) / 32, 256, 0, stream>>>(x12h, x34h, BtA, ab1, aW2, emb);
}